// Round 13
// baseline (441.386 us; speedup 1.0000x reference)
//
#include <hip/hip_runtime.h>

typedef __bf16 bf16x8 __attribute__((ext_vector_type(8)));
typedef float f32x4 __attribute__((ext_vector_type(4)));
typedef int i32x4 __attribute__((ext_vector_type(4)));

#define DEV __device__ __forceinline__
#define AS1 __attribute__((address_space(1)))
#define AS3 __attribute__((address_space(3)))

DEV unsigned short f2bf(float f) {
  union { float f; unsigned u; } x; x.f = f;
  unsigned r = x.u + 0x7fffu + ((x.u >> 16) & 1u);
  return (unsigned short)(r >> 16);
}

DEV unsigned pkbf(float a, float b) {  // packs {lo=a, hi=b} as 2x bf16 (RNE)
  unsigned r;
  asm("v_cvt_pk_bf16_f32 %0, %1, %2" : "=v"(r) : "v"(a), "v"(b));
  return r;
}

DEV f32x4 mfma16(bf16x8 a, bf16x8 b, f32x4 c) {
  return __builtin_amdgcn_mfma_f32_16x16x32_bf16(a, b, c, 0, 0, 0);
}

#if __has_builtin(__builtin_amdgcn_exp2f)
DEV float xexp2(float x) { return __builtin_amdgcn_exp2f(x); }
#else
DEV float xexp2(float x) { return __expf(x * 0.6931471805599453f); }
#endif

DEV void gload16(const void* g, void* lds) {
  __builtin_amdgcn_global_load_lds((const AS1 void*)g, (AS3 void*)lds, 16, 0, 0);
}

// ---------------- fp32 -> bf16 conversion ----------------
__global__ void f2b_kernel(const float* __restrict__ src, unsigned short* __restrict__ dst, int n) {
  int i = (blockIdx.x * blockDim.x + threadIdx.x) * 4;
  int stride = gridDim.x * blockDim.x * 4;
  for (; i < n; i += stride) {
    float4 v = *reinterpret_cast<const float4*>(src + i);
    ushort4 o;
    o.x = f2bf(v.x); o.y = f2bf(v.y); o.z = f2bf(v.z); o.w = f2bf(v.w);
    *reinterpret_cast<ushort4*>(dst + i) = o;
  }
}

// ---------------- GEMM (m97 structure): C[M,N] = A[M,K] * B[N,K]^T + bias ----------------
// EPI 0: fp32 row-major [M][N].
// EPI 1: qkv scatter. Q (s=0): [bh][t][64] bf16, PRE-SCALED by 0.125*log2(e).
//        K (s=1): [64+bh][t][64].  V (s=2): TRANSPOSED [128+bh][64 d][2048 t].
template <int EPI>
__global__ __launch_bounds__(256, 3)
void gemm_bt(const unsigned short* __restrict__ A, const unsigned short* __restrict__ B,
             const float* __restrict__ bias, void* __restrict__ outv,
             int M, int N, int K) {
  __shared__ __align__(16) unsigned short As[128 * 64];
  __shared__ __align__(16) unsigned short Bs[128 * 64];
  const int tid = threadIdx.x;
  const int l = tid & 63, w = tid >> 6;
  const int wr = w >> 1, wc = w & 1;
  const int tm = blockIdx.x * 128, tn = blockIdx.y * 128;
  const int lr = l >> 3, lc = (l & 7) * 8;

  f32x4 acc[4][4] = {};

  for (int kt = 0; kt < K; kt += 64) {
#pragma unroll
    for (int i = 0; i < 4; ++i) {
      int c = i * 4 + w;
      gload16(A + (size_t)(tm + c * 8 + lr) * K + kt + lc, (char*)As + c * 1024);
    }
#pragma unroll
    for (int i = 0; i < 4; ++i) {
      int c = i * 4 + w;
      gload16(B + (size_t)(tn + c * 8 + lr) * K + kt + lc, (char*)Bs + c * 1024);
    }
    __syncthreads();
#pragma unroll
    for (int ks = 0; ks < 2; ++ks) {
      int ko = ks * 32 + (l >> 4) * 8;
      bf16x8 af[4], bfr[4];
#pragma unroll
      for (int i = 0; i < 4; ++i) {
        af[i]  = *reinterpret_cast<const bf16x8*>(As + (wr * 64 + i * 16 + (l & 15)) * 64 + ko);
        bfr[i] = *reinterpret_cast<const bf16x8*>(Bs + (wc * 64 + i * 16 + (l & 15)) * 64 + ko);
      }
#pragma unroll
      for (int mi = 0; mi < 4; ++mi)
#pragma unroll
        for (int ni = 0; ni < 4; ++ni)
          acc[mi][ni] = mfma16(af[mi], bfr[ni], acc[mi][ni]);
    }
    __syncthreads();
  }

#pragma unroll
  for (int ni = 0; ni < 4; ++ni) {
    int n = tn + wc * 64 + ni * 16 + (l & 15);
    float bv = bias[n];
    if (EPI == 0) {
      float* out = (float*)outv;
#pragma unroll
      for (int mi = 0; mi < 4; ++mi)
#pragma unroll
        for (int r = 0; r < 4; ++r) {
          int m = tm + wr * 64 + mi * 16 + (l >> 4) * 4 + r;
          out[(size_t)m * N + n] = acc[mi][ni][r] + bv;
        }
    } else {
      unsigned short* out = (unsigned short*)outv;
      int s = n >> 10, rem = n & 1023, h = rem >> 6, d = rem & 63;
      if (s == 2) {
        // V transposed: [128 + bh][d][t], 4 consecutive t per lane -> ushort4
#pragma unroll
        for (int mi = 0; mi < 4; ++mi) {
          int m = tm + wr * 64 + mi * 16 + (l >> 4) * 4;
          int bb = m >> 11, t = m & 2047;
          ushort4 pv;
          pv.x = f2bf(acc[mi][ni][0] + bv);
          pv.y = f2bf(acc[mi][ni][1] + bv);
          pv.z = f2bf(acc[mi][ni][2] + bv);
          pv.w = f2bf(acc[mi][ni][3] + bv);
          size_t off = ((size_t)(128 + bb * 16 + h)) * 131072 + (size_t)d * 2048 + t;
          *reinterpret_cast<ushort4*>(out + off) = pv;
        }
      } else {
        const float sc = (s == 0) ? 0.1803368801f : 1.0f;  // fold 0.125*log2(e) into Q
#pragma unroll
        for (int mi = 0; mi < 4; ++mi)
#pragma unroll
          for (int r = 0; r < 4; ++r) {
            int m = tm + wr * 64 + mi * 16 + (l >> 4) * 4 + r;
            int bb = m >> 11, t = m & 2047;
            size_t off = ((((size_t)s * 4 + bb) * 16 + h) * 2048 + t) * 64 + d;
            out[off] = f2bf((acc[mi][ni][r] + bv) * sc);
          }
      }
    }
  }
}

// ---------------- Attention ----------------
// 1024 blocks 1-D, XCD-chunked; qt order 15,0,14,1,... (store smoothing).
// 4 waves x 32 q-rows; Q in regs (pre-scaled). Arena 40KB -> 4 blocks/CU.
// Pass 1: BK=128 2-ring + interleaved zero-fill.
// Pass 2: K/V^T dbuf prefetch + per-wave vmcnt(8) + s_barrier; PV split by
//         qB-half (Ps = 2KB/wave) to fit the 40KB arena.
__global__ __launch_bounds__(256, 4)
void attn_kernel(const unsigned short* __restrict__ qkv, float* __restrict__ attnW,
                 unsigned short* __restrict__ Ob) {
  __shared__ __align__(16) char smem[40960];
  // pass 1: ring {0,1}*16384
  // pass 2: Ks dbuf {0,1}*8192; VsT dbuf 16384+{0,1}*8192; Ps @32768 + w*2048

  const int tid = threadIdx.x, l = tid & 63, w = tid >> 6;
  const int li = l & 15, g = l >> 4;
  const int dd = blockIdx.x;
  const int bh = (dd & 7) + ((dd >> 3) & 7) * 8;
  const int sl6 = dd >> 6;
  const int qt = (sl6 & 1) ? (sl6 >> 1) : (15 - (sl6 >> 1));  // 15,0,14,1,13,2,...
  const int b = bh >> 4, hh = bh & 15;
  const size_t plane = (size_t)2048 * 64;
  const unsigned short* Qg  = qkv + (size_t)bh * plane;
  const unsigned short* Kg  = qkv + ((size_t)64 + bh) * plane;
  const unsigned short* VTg = qkv + ((size_t)128 + bh) * plane;  // [64 d][2048 t]
  const int q0 = qt * 128;
  const int nkt = 2 * qt + 2;

  // ---- Q fragments in registers (wave-private rows; already scaled) ----
  bf16x8 bq[2][2];
#pragma unroll
  for (int qB = 0; qB < 2; ++qB)
#pragma unroll
    for (int ks = 0; ks < 2; ++ks) {
      int cc = ks * 4 + g;
      bq[qB][ks] = *reinterpret_cast<const bf16x8*>(
          Qg + (size_t)(q0 + w * 32 + qB * 16 + li) * 64 + cc * 8);
    }

  auto stageK = [&](int kt64, char* base) {
#pragma unroll
    for (int it = 0; it < 2; ++it) {
      int c = it * 4 + w;
      int X = c * 1024 + l * 16;
      int row = X >> 7, sl = (X >> 4) & 7;
      gload16(Kg + (size_t)(kt64 * 64 + row) * 64 + ((sl ^ (row & 7)) * 8), base + c * 1024);
    }
  };
  auto stageK128 = [&](int kt128, char* base) {
#pragma unroll
    for (int it = 0; it < 4; ++it) {
      int c = it * 4 + w;
      int X = c * 1024 + l * 16;
      int row = X >> 7, sl = (X >> 4) & 7;
      gload16(Kg + (size_t)(kt128 * 128 + row) * 64 + ((sl ^ (row & 7)) * 8), base + c * 1024);
    }
  };
  auto stageVT = [&](int kt64, char* base) {
#pragma unroll
    for (int it = 0; it < 2; ++it) {
      int c = it * 4 + w;
      int X = c * 1024 + l * 16;
      int row = X >> 7, sl = (X >> 4) & 7;   // row = d
      gload16(VTg + (size_t)row * 2048 + kt64 * 64 + ((sl ^ (row & 7)) * 8), base + c * 1024);
    }
  };

  auto computeS = [&](const char* base, f32x4 s[4][2]) {
    const unsigned short* Kp = (const unsigned short*)base;
#pragma unroll
    for (int ks = 0; ks < 2; ++ks) {
      bf16x8 ak[4];
      int cc = ks * 4 + g;
#pragma unroll
      for (int kA = 0; kA < 4; ++kA) {
        int kr = kA * 16 + li;
        ak[kA] = *reinterpret_cast<const bf16x8*>(Kp + kr * 64 + ((cc ^ (kr & 7)) * 8));
      }
#pragma unroll
      for (int kA = 0; kA < 4; ++kA)
#pragma unroll
        for (int qB = 0; qB < 2; ++qB)
          s[kA][qB] = mfma16(ak[kA], bq[qB][ks], s[kA][qB]);
    }
  };

  // zero-fill geometry (masked cols >= col0), sliced across pass-1 tiles
  const int col0 = 128 * (qt + 1);
  const int cpr = (2048 - col0) >> 2;        // f32x4 chunks per row (0 for qt=15)
  const int nkt1 = qt + 1;
  const int rpt = (128 + nkt1 - 1) / nkt1;   // rows per pass-1 tile

  // ---- pass 1: row denominators (m = 0), BK=128, 2-ring + interleaved zero-fill ----
  float lsum[2] = {0.f, 0.f};
  {
    stageK128(0, smem);
    asm volatile("s_waitcnt vmcnt(0)" ::: "memory");
    asm volatile("s_barrier" ::: "memory");
    int cb1 = 0;
    for (int kt = 0; kt < nkt1; ++kt) {
      const int nb1 = cb1 ^ 1;
      if (kt + 1 < nkt1) stageK128(kt + 1, smem + nb1 * 16384);

      // interleaved zero-fill slice (stores overlap this tile's compute)
      if (cpr > 0) {
        int r0 = kt * rpt;
        int r1 = r0 + rpt; if (r1 > 128) r1 = 128;
        f32x4 z = {0.f, 0.f, 0.f, 0.f};
        for (int row = r0; row < r1; ++row) {
          size_t base = ((size_t)bh * 2048 + (q0 + row)) * 2048 + col0;
          for (int c = tid; c < cpr; c += 256)
            __builtin_nontemporal_store(z, reinterpret_cast<f32x4*>(attnW + base + (size_t)c * 4));
        }
      }

      const bool dg = (kt == qt);
#pragma unroll
      for (int half = 0; half < 2; ++half) {
        f32x4 s[4][2] = {};
        computeS(smem + cb1 * 16384 + half * 8192, s);
#pragma unroll
        for (int qB = 0; qB < 2; ++qB) {
          int qg = q0 + w * 32 + qB * 16 + li;
          float a = 0.f;
#pragma unroll
          for (int kA = 0; kA < 4; ++kA)
#pragma unroll
            for (int r = 0; r < 4; ++r) {
              float e = xexp2(s[kA][qB][r]);
              if (dg) { int k = kt * 128 + half * 64 + kA * 16 + g * 4 + r; e = (k <= qg) ? e : 0.f; }
              a += e;
            }
          lsum[qB] += a;
        }
      }
      asm volatile("s_waitcnt vmcnt(0)" ::: "memory");
      asm volatile("s_barrier" ::: "memory");
      cb1 = nb1;
    }
  }

  float linv[2];
#pragma unroll
  for (int qB = 0; qB < 2; ++qB) {
    float v = lsum[qB];
    v += __shfl_xor(v, 16, 64);
    v += __shfl_xor(v, 32, 64);
    linv[qB] = 1.0f / v;
  }

  // ---- pass 2: attnW stores + O = P@V, K/V dbuf + counted vmcnt ----
  __syncthreads();  // full drain before arena re-carve
  char* KsB = smem;                       // dbuf {0,1}*8192
  char* VsB = smem + 16384;               // dbuf {0,1}*8192
  unsigned short* PsW = (unsigned short*)(smem + 32768 + w * 2048);  // 16 rows x 128B

  stageK(0, KsB);
  stageVT(0, VsB);
  asm volatile("" ::: "memory");
  asm volatile("s_waitcnt vmcnt(0)" ::: "memory");
  asm volatile("s_barrier" ::: "memory");

  f32x4 o[2][4] = {};
  int cb = 0;

  for (int kt = 0; kt < nkt; ++kt) {
    const int nb = cb ^ 1;
    if (kt + 1 < nkt) { stageK(kt + 1, KsB + nb * 8192); stageVT(kt + 1, VsB + nb * 8192); }
    asm volatile("" ::: "memory");  // pin gload issue before stores

    f32x4 s[4][2] = {};
    computeS(KsB + cb * 8192, s);

    const bool dg = (kt >= 2 * qt);
    const unsigned short* Vp = (const unsigned short*)(VsB + cb * 8192);

    // per qB-half: softmax + attnW store + Ps write, then PV for that half
#pragma unroll
    for (int qB = 0; qB < 2; ++qB) {
      int qg = q0 + w * 32 + qB * 16 + li;
#pragma unroll
      for (int kA = 0; kA < 4; ++kA) {
        f32x4 e;
#pragma unroll
        for (int r = 0; r < 4; ++r) {
          float v = xexp2(s[kA][qB][r]) * linv[qB];
          if (dg) { int k = kt * 64 + kA * 16 + g * 4 + r; v = (k <= qg) ? v : 0.f; }
          e[r] = v;
        }
        __builtin_nontemporal_store(e, reinterpret_cast<f32x4*>(
            attnW + ((size_t)bh * 2048 + qg) * 2048 + kt * 64 + kA * 16 + g * 4));
        uint2 pk;
        pk.x = pkbf(e[0], e[1]);
        pk.y = pkbf(e[2], e[3]);
        *reinterpret_cast<uint2*>((char*)PsW + li * 128 + ((kA * 32 + g * 8) ^ ((li & 7) << 4))) = pk;
      }

      __builtin_amdgcn_wave_barrier();  // Ps wave-private RAW: pin schedule

      // O^T(qB) += V^T x P^T(qB)
#pragma unroll
      for (int ks = 0; ks < 2; ++ks) {
        int cc = ks * 4 + g;
        bf16x8 bp = *reinterpret_cast<const bf16x8*>(
            (const char*)PsW + li * 128 + ((ks * 64 + g * 16) ^ ((li & 7) << 4)));
#pragma unroll
        for (int df = 0; df < 4; ++df) {
          int dr = df * 16 + li;
          bf16x8 av = *reinterpret_cast<const bf16x8*>(Vp + dr * 64 + ((cc ^ (dr & 7)) * 8));
          o[qB][df] = mfma16(av, bp, o[qB][df]);
        }
      }
      __builtin_amdgcn_wave_barrier();  // Ps reuse across qB halves: pin schedule
    }

    // retire: prev-tile stores + this tile's 4 gloads; leave this tile's 8 stores in flight.
    // s_barrier AFTER the wait gives cross-wave visibility (vmcnt is per-wave).
    asm volatile("s_waitcnt vmcnt(8)" ::: "memory");
    asm volatile("s_barrier" ::: "memory");
    cb = nb;
  }

  // ---- O store: lane holds q = qB*16+li, d = df*16 + g*4 + r (O^T layout) ----
#pragma unroll
  for (int qB = 0; qB < 2; ++qB) {
    int qg = q0 + w * 32 + qB * 16 + li;
#pragma unroll
    for (int df = 0; df < 4; ++df) {
      ushort4 ov;
      ov.x = f2bf(o[qB][df][0]);
      ov.y = f2bf(o[qB][df][1]);
      ov.z = f2bf(o[qB][df][2]);
      ov.w = f2bf(o[qB][df][3]);
      *reinterpret_cast<ushort4*>(Ob + ((size_t)b * 2048 + qg) * 1024 + hh * 64 + df * 16 + g * 4) = ov;
    }
  }
}

extern "C" void kernel_launch(void* const* d_in, const int* in_sizes, int n_in,
                              void* d_out, int out_size, void* d_ws, size_t ws_size,
                              hipStream_t stream) {
  const float* x  = (const float*)d_in[0];
  const float* w1 = (const float*)d_in[1];
  const float* b1 = (const float*)d_in[2];
  const float* w2 = (const float*)d_in[3];
  const float* b2 = (const float*)d_in[4];
  float* out = (float*)d_out;
  float* attnW = out + (size_t)8192 * 1024;

  unsigned short* xb   = (unsigned short*)d_ws;
  unsigned short* w1b  = xb + (size_t)8192 * 1024;
  unsigned short* w2b  = w1b + (size_t)3072 * 1024;
  unsigned short* qkvb = w2b + (size_t)1024 * 1024;
  unsigned short* ob   = qkvb + (size_t)3 * 8192 * 1024;

  f2b_kernel<<<1024, 256, 0, stream>>>(x, xb, 8192 * 1024);
  f2b_kernel<<<512, 256, 0, stream>>>(w1, w1b, 3072 * 1024);

  gemm_bt<1><<<dim3(64, 24), 256, 0, stream>>>(xb, w1b, b1, qkvb, 8192, 3072, 1024);

  // w2 conversion rides alongside the attention kernel's early blocks
  f2b_kernel<<<256, 256, 0, stream>>>(w2, w2b, 1024 * 1024);

  attn_kernel<<<1024, 256, 0, stream>>>(qkvb, attnW, ob);

  gemm_bt<0><<<dim3(64, 8), 256, 0, stream>>>(ob, w2b, b2, out, 8192, 1024, 1024);
}

// Round 14
// 385.169 us; speedup vs baseline: 1.1460x; 1.1460x over previous
//
#include <hip/hip_runtime.h>

typedef __bf16 bf16x8 __attribute__((ext_vector_type(8)));
typedef float f32x4 __attribute__((ext_vector_type(4)));
typedef int i32x4 __attribute__((ext_vector_type(4)));

#define DEV __device__ __forceinline__
#define AS1 __attribute__((address_space(1)))
#define AS3 __attribute__((address_space(3)))

DEV unsigned short f2bf(float f) {
  union { float f; unsigned u; } x; x.f = f;
  unsigned r = x.u + 0x7fffu + ((x.u >> 16) & 1u);
  return (unsigned short)(r >> 16);
}

DEV unsigned pkbf(float a, float b) {  // packs {lo=a, hi=b} as 2x bf16 (RNE)
  unsigned r;
  asm("v_cvt_pk_bf16_f32 %0, %1, %2" : "=v"(r) : "v"(a), "v"(b));
  return r;
}

DEV f32x4 mfma16(bf16x8 a, bf16x8 b, f32x4 c) {
  return __builtin_amdgcn_mfma_f32_16x16x32_bf16(a, b, c, 0, 0, 0);
}

#if __has_builtin(__builtin_amdgcn_exp2f)
DEV float xexp2(float x) { return __builtin_amdgcn_exp2f(x); }
#else
DEV float xexp2(float x) { return __expf(x * 0.6931471805599453f); }
#endif

DEV void gload16(const void* g, void* lds) {
  __builtin_amdgcn_global_load_lds((const AS1 void*)g, (AS3 void*)lds, 16, 0, 0);
}

// ---------------- fp32 -> bf16 conversion ----------------
__global__ void f2b_kernel(const float* __restrict__ src, unsigned short* __restrict__ dst, int n) {
  int i = (blockIdx.x * blockDim.x + threadIdx.x) * 4;
  int stride = gridDim.x * blockDim.x * 4;
  for (; i < n; i += stride) {
    float4 v = *reinterpret_cast<const float4*>(src + i);
    ushort4 o;
    o.x = f2bf(v.x); o.y = f2bf(v.y); o.z = f2bf(v.z); o.w = f2bf(v.w);
    *reinterpret_cast<ushort4*>(dst + i) = o;
  }
}

// ---------------- GEMM (m97 structure): C[M,N] = A[M,K] * B[N,K]^T + bias ----------------
// EPI 0: fp32 row-major [M][N].
// EPI 1: qkv scatter. Q (s=0): [bh][t][64] bf16, PRE-SCALED by 0.125*log2(e).
//        K (s=1): [64+bh][t][64].  V (s=2): TRANSPOSED [128+bh][64 d][2048 t].
template <int EPI>
__global__ __launch_bounds__(256, 3)
void gemm_bt(const unsigned short* __restrict__ A, const unsigned short* __restrict__ B,
             const float* __restrict__ bias, void* __restrict__ outv,
             int M, int N, int K) {
  __shared__ __align__(16) unsigned short As[128 * 64];
  __shared__ __align__(16) unsigned short Bs[128 * 64];
  const int tid = threadIdx.x;
  const int l = tid & 63, w = tid >> 6;
  const int wr = w >> 1, wc = w & 1;
  const int tm = blockIdx.x * 128, tn = blockIdx.y * 128;
  const int lr = l >> 3, lc = (l & 7) * 8;

  f32x4 acc[4][4] = {};

  for (int kt = 0; kt < K; kt += 64) {
#pragma unroll
    for (int i = 0; i < 4; ++i) {
      int c = i * 4 + w;
      gload16(A + (size_t)(tm + c * 8 + lr) * K + kt + lc, (char*)As + c * 1024);
    }
#pragma unroll
    for (int i = 0; i < 4; ++i) {
      int c = i * 4 + w;
      gload16(B + (size_t)(tn + c * 8 + lr) * K + kt + lc, (char*)Bs + c * 1024);
    }
    __syncthreads();
#pragma unroll
    for (int ks = 0; ks < 2; ++ks) {
      int ko = ks * 32 + (l >> 4) * 8;
      bf16x8 af[4], bfr[4];
#pragma unroll
      for (int i = 0; i < 4; ++i) {
        af[i]  = *reinterpret_cast<const bf16x8*>(As + (wr * 64 + i * 16 + (l & 15)) * 64 + ko);
        bfr[i] = *reinterpret_cast<const bf16x8*>(Bs + (wc * 64 + i * 16 + (l & 15)) * 64 + ko);
      }
#pragma unroll
      for (int mi = 0; mi < 4; ++mi)
#pragma unroll
        for (int ni = 0; ni < 4; ++ni)
          acc[mi][ni] = mfma16(af[mi], bfr[ni], acc[mi][ni]);
    }
    __syncthreads();
  }

#pragma unroll
  for (int ni = 0; ni < 4; ++ni) {
    int n = tn + wc * 64 + ni * 16 + (l & 15);
    float bv = bias[n];
    if (EPI == 0) {
      float* out = (float*)outv;
#pragma unroll
      for (int mi = 0; mi < 4; ++mi)
#pragma unroll
        for (int r = 0; r < 4; ++r) {
          int m = tm + wr * 64 + mi * 16 + (l >> 4) * 4 + r;
          out[(size_t)m * N + n] = acc[mi][ni][r] + bv;
        }
    } else {
      unsigned short* out = (unsigned short*)outv;
      int s = n >> 10, rem = n & 1023, h = rem >> 6, d = rem & 63;
      if (s == 2) {
        // V transposed: [128 + bh][d][t], 4 consecutive t per lane -> ushort4
#pragma unroll
        for (int mi = 0; mi < 4; ++mi) {
          int m = tm + wr * 64 + mi * 16 + (l >> 4) * 4;
          int bb = m >> 11, t = m & 2047;
          ushort4 pv;
          pv.x = f2bf(acc[mi][ni][0] + bv);
          pv.y = f2bf(acc[mi][ni][1] + bv);
          pv.z = f2bf(acc[mi][ni][2] + bv);
          pv.w = f2bf(acc[mi][ni][3] + bv);
          size_t off = ((size_t)(128 + bb * 16 + h)) * 131072 + (size_t)d * 2048 + t;
          *reinterpret_cast<ushort4*>(out + off) = pv;
        }
      } else {
        const float sc = (s == 0) ? 0.1803368801f : 1.0f;  // fold 0.125*log2(e) into Q
#pragma unroll
        for (int mi = 0; mi < 4; ++mi)
#pragma unroll
          for (int r = 0; r < 4; ++r) {
            int m = tm + wr * 64 + mi * 16 + (l >> 4) * 4 + r;
            int bb = m >> 11, t = m & 2047;
            size_t off = ((((size_t)s * 4 + bb) * 16 + h) * 2048 + t) * 64 + d;
            out[off] = f2bf((acc[mi][ni][r] + bv) * sc);
          }
      }
    }
  }
}

// ---------------- Attention ----------------
// 1024 blocks 1-D, XCD-chunked; qt order 15,0,14,1,... (store smoothing).
// 4 waves x 32 q-rows; Q in regs (pre-scaled). Arena 48KB -> 3 blocks/CU.
// Pass 1: BK=128 2-ring + interleaved zero-fill (nt stores, 1KB/instr coalesced).
// Pass 2: K/V^T dbuf prefetch + per-wave vmcnt(8) + s_barrier; P stores are
//         NORMAL (cached) stores -> L2 write-combines the 64B lane segments.
__global__ __launch_bounds__(256, 3)
void attn_kernel(const unsigned short* __restrict__ qkv, float* __restrict__ attnW,
                 unsigned short* __restrict__ Ob) {
  __shared__ __align__(16) char smem[49152];
  // pass 1: ring {0,1}*16384
  // pass 2: Ks dbuf {0,1}*8192; VsT dbuf 16384+{0,1}*8192; Ps @32768 + w*4096

  const int tid = threadIdx.x, l = tid & 63, w = tid >> 6;
  const int li = l & 15, g = l >> 4;
  const int dd = blockIdx.x;
  const int bh = (dd & 7) + ((dd >> 3) & 7) * 8;
  const int sl6 = dd >> 6;
  const int qt = (sl6 & 1) ? (sl6 >> 1) : (15 - (sl6 >> 1));  // 15,0,14,1,13,2,...
  const int b = bh >> 4, hh = bh & 15;
  const size_t plane = (size_t)2048 * 64;
  const unsigned short* Qg  = qkv + (size_t)bh * plane;
  const unsigned short* Kg  = qkv + ((size_t)64 + bh) * plane;
  const unsigned short* VTg = qkv + ((size_t)128 + bh) * plane;  // [64 d][2048 t]
  const int q0 = qt * 128;
  const int nkt = 2 * qt + 2;

  // ---- Q fragments in registers (wave-private rows; already scaled) ----
  bf16x8 bq[2][2];
#pragma unroll
  for (int qB = 0; qB < 2; ++qB)
#pragma unroll
    for (int ks = 0; ks < 2; ++ks) {
      int cc = ks * 4 + g;
      bq[qB][ks] = *reinterpret_cast<const bf16x8*>(
          Qg + (size_t)(q0 + w * 32 + qB * 16 + li) * 64 + cc * 8);
    }

  auto stageK = [&](int kt64, char* base) {
#pragma unroll
    for (int it = 0; it < 2; ++it) {
      int c = it * 4 + w;
      int X = c * 1024 + l * 16;
      int row = X >> 7, sl = (X >> 4) & 7;
      gload16(Kg + (size_t)(kt64 * 64 + row) * 64 + ((sl ^ (row & 7)) * 8), base + c * 1024);
    }
  };
  auto stageK128 = [&](int kt128, char* base) {
#pragma unroll
    for (int it = 0; it < 4; ++it) {
      int c = it * 4 + w;
      int X = c * 1024 + l * 16;
      int row = X >> 7, sl = (X >> 4) & 7;
      gload16(Kg + (size_t)(kt128 * 128 + row) * 64 + ((sl ^ (row & 7)) * 8), base + c * 1024);
    }
  };
  auto stageVT = [&](int kt64, char* base) {
#pragma unroll
    for (int it = 0; it < 2; ++it) {
      int c = it * 4 + w;
      int X = c * 1024 + l * 16;
      int row = X >> 7, sl = (X >> 4) & 7;   // row = d
      gload16(VTg + (size_t)row * 2048 + kt64 * 64 + ((sl ^ (row & 7)) * 8), base + c * 1024);
    }
  };

  auto computeS = [&](const char* base, f32x4 s[4][2]) {
    const unsigned short* Kp = (const unsigned short*)base;
#pragma unroll
    for (int ks = 0; ks < 2; ++ks) {
      bf16x8 ak[4];
      int cc = ks * 4 + g;
#pragma unroll
      for (int kA = 0; kA < 4; ++kA) {
        int kr = kA * 16 + li;
        ak[kA] = *reinterpret_cast<const bf16x8*>(Kp + kr * 64 + ((cc ^ (kr & 7)) * 8));
      }
#pragma unroll
      for (int kA = 0; kA < 4; ++kA)
#pragma unroll
        for (int qB = 0; qB < 2; ++qB)
          s[kA][qB] = mfma16(ak[kA], bq[qB][ks], s[kA][qB]);
    }
  };

  // zero-fill geometry (masked cols >= col0), sliced across pass-1 tiles
  const int col0 = 128 * (qt + 1);
  const int cpr = (2048 - col0) >> 2;        // f32x4 chunks per row (0 for qt=15)
  const int nkt1 = qt + 1;
  const int rpt = (128 + nkt1 - 1) / nkt1;   // rows per pass-1 tile

  // ---- pass 1: row denominators (m = 0), BK=128, 2-ring + interleaved zero-fill ----
  float lsum[2] = {0.f, 0.f};
  {
    stageK128(0, smem);
    asm volatile("s_waitcnt vmcnt(0)" ::: "memory");
    asm volatile("s_barrier" ::: "memory");
    int cb1 = 0;
    for (int kt = 0; kt < nkt1; ++kt) {
      const int nb1 = cb1 ^ 1;
      if (kt + 1 < nkt1) stageK128(kt + 1, smem + nb1 * 16384);

      // interleaved zero-fill slice (stores overlap this tile's compute)
      if (cpr > 0) {
        int r0 = kt * rpt;
        int r1 = r0 + rpt; if (r1 > 128) r1 = 128;
        f32x4 z = {0.f, 0.f, 0.f, 0.f};
        for (int row = r0; row < r1; ++row) {
          size_t base = ((size_t)bh * 2048 + (q0 + row)) * 2048 + col0;
          for (int c = tid; c < cpr; c += 256)
            __builtin_nontemporal_store(z, reinterpret_cast<f32x4*>(attnW + base + (size_t)c * 4));
        }
      }

      const bool dg = (kt == qt);
#pragma unroll
      for (int half = 0; half < 2; ++half) {
        f32x4 s[4][2] = {};
        computeS(smem + cb1 * 16384 + half * 8192, s);
#pragma unroll
        for (int qB = 0; qB < 2; ++qB) {
          int qg = q0 + w * 32 + qB * 16 + li;
          float a = 0.f;
#pragma unroll
          for (int kA = 0; kA < 4; ++kA)
#pragma unroll
            for (int r = 0; r < 4; ++r) {
              float e = xexp2(s[kA][qB][r]);
              if (dg) { int k = kt * 128 + half * 64 + kA * 16 + g * 4 + r; e = (k <= qg) ? e : 0.f; }
              a += e;
            }
          lsum[qB] += a;
        }
      }
      asm volatile("s_waitcnt vmcnt(0)" ::: "memory");
      asm volatile("s_barrier" ::: "memory");
      cb1 = nb1;
    }
  }

  float linv[2];
#pragma unroll
  for (int qB = 0; qB < 2; ++qB) {
    float v = lsum[qB];
    v += __shfl_xor(v, 16, 64);
    v += __shfl_xor(v, 32, 64);
    linv[qB] = 1.0f / v;
  }

  // ---- pass 2: attnW stores + O = P@V, K/V dbuf + counted vmcnt ----
  __syncthreads();  // full drain before arena re-carve
  char* KsB = smem;                       // dbuf {0,1}*8192
  char* VsB = smem + 16384;               // dbuf {0,1}*8192
  unsigned short* PsW = (unsigned short*)(smem + 32768 + w * 4096);

  stageK(0, KsB);
  stageVT(0, VsB);
  asm volatile("" ::: "memory");
  asm volatile("s_waitcnt vmcnt(0)" ::: "memory");
  asm volatile("s_barrier" ::: "memory");

  f32x4 o[2][4] = {};
  int cb = 0;

  for (int kt = 0; kt < nkt; ++kt) {
    const int nb = cb ^ 1;
    if (kt + 1 < nkt) { stageK(kt + 1, KsB + nb * 8192); stageVT(kt + 1, VsB + nb * 8192); }
    asm volatile("" ::: "memory");  // pin gload issue before stores

    f32x4 s[4][2] = {};
    computeS(KsB + cb * 8192, s);

    const bool dg = (kt >= 2 * qt);
#pragma unroll
    for (int kA = 0; kA < 4; ++kA)
#pragma unroll
      for (int qB = 0; qB < 2; ++qB) {
        int qg = q0 + w * 32 + qB * 16 + li;
        f32x4 e;
#pragma unroll
        for (int r = 0; r < 4; ++r) {
          float v = xexp2(s[kA][qB][r]) * linv[qB];
          if (dg) { int k = kt * 64 + kA * 16 + g * 4 + r; v = (k <= qg) ? v : 0.f; }
          e[r] = v;
        }
        // NORMAL store: L2 write-allocate combines the 64B lane segments
        *reinterpret_cast<f32x4*>(
            attnW + ((size_t)bh * 2048 + qg) * 2048 + kt * 64 + kA * 16 + g * 4) = e;
        uint2 pk;
        pk.x = pkbf(e[0], e[1]);
        pk.y = pkbf(e[2], e[3]);
        int qr = qB * 16 + li;
        *reinterpret_cast<uint2*>((char*)PsW + qr * 128 + ((kA * 32 + g * 8) ^ ((qr & 7) << 4))) = pk;
      }

    __builtin_amdgcn_wave_barrier();  // Ps wave-private RAW: pin schedule

    // O^T += V^T x P^T
    const unsigned short* Vp = (const unsigned short*)(VsB + cb * 8192);
#pragma unroll
    for (int ks = 0; ks < 2; ++ks) {
      int cc = ks * 4 + g;
      bf16x8 av[4], bp[2];
#pragma unroll
      for (int df = 0; df < 4; ++df) {
        int dr = df * 16 + li;
        av[df] = *reinterpret_cast<const bf16x8*>(Vp + dr * 64 + ((cc ^ (dr & 7)) * 8));
      }
#pragma unroll
      for (int qB = 0; qB < 2; ++qB) {
        int qr = qB * 16 + li;
        bp[qB] = *reinterpret_cast<const bf16x8*>((const char*)PsW + qr * 128 + ((ks * 64 + g * 16) ^ ((qr & 7) << 4)));
      }
#pragma unroll
      for (int qB = 0; qB < 2; ++qB)
#pragma unroll
        for (int df = 0; df < 4; ++df)
          o[qB][df] = mfma16(av[df], bp[qB], o[qB][df]);
    }

    // retire: prev-tile stores + this tile's 4 gloads; leave this tile's 8 stores in flight.
    // s_barrier AFTER the wait gives cross-wave visibility (vmcnt is per-wave).
    asm volatile("s_waitcnt vmcnt(8)" ::: "memory");
    asm volatile("s_barrier" ::: "memory");
    cb = nb;
  }

  // ---- O store: lane holds q = qB*16+li, d = df*16 + g*4 + r (O^T layout) ----
#pragma unroll
  for (int qB = 0; qB < 2; ++qB) {
    int qg = q0 + w * 32 + qB * 16 + li;
#pragma unroll
    for (int df = 0; df < 4; ++df) {
      ushort4 ov;
      ov.x = f2bf(o[qB][df][0]);
      ov.y = f2bf(o[qB][df][1]);
      ov.z = f2bf(o[qB][df][2]);
      ov.w = f2bf(o[qB][df][3]);
      *reinterpret_cast<ushort4*>(Ob + ((size_t)b * 2048 + qg) * 1024 + hh * 64 + df * 16 + g * 4) = ov;
    }
  }
}

extern "C" void kernel_launch(void* const* d_in, const int* in_sizes, int n_in,
                              void* d_out, int out_size, void* d_ws, size_t ws_size,
                              hipStream_t stream) {
  const float* x  = (const float*)d_in[0];
  const float* w1 = (const float*)d_in[1];
  const float* b1 = (const float*)d_in[2];
  const float* w2 = (const float*)d_in[3];
  const float* b2 = (const float*)d_in[4];
  float* out = (float*)d_out;
  float* attnW = out + (size_t)8192 * 1024;

  unsigned short* xb   = (unsigned short*)d_ws;
  unsigned short* w1b  = xb + (size_t)8192 * 1024;
  unsigned short* w2b  = w1b + (size_t)3072 * 1024;
  unsigned short* qkvb = w2b + (size_t)1024 * 1024;
  unsigned short* ob   = qkvb + (size_t)3 * 8192 * 1024;

  f2b_kernel<<<1024, 256, 0, stream>>>(x, xb, 8192 * 1024);
  f2b_kernel<<<512, 256, 0, stream>>>(w1, w1b, 3072 * 1024);

  gemm_bt<1><<<dim3(64, 24), 256, 0, stream>>>(xb, w1b, b1, qkvb, 8192, 3072, 1024);

  // w2 conversion rides alongside the attention kernel's early blocks
  f2b_kernel<<<256, 256, 0, stream>>>(w2, w2b, 1024 * 1024);

  attn_kernel<<<1024, 256, 0, stream>>>(qkvb, attnW, ob);

  gemm_bt<0><<<dim3(64, 8), 256, 0, stream>>>(ob, w2b, b2, out, 8192, 1024, 1024);
}